// Round 5
// baseline (593.010 us; speedup 1.0000x reference)
//
#include <hip/hip_runtime.h>

// GCN 2-layer: x[N,128] @ W1[128,64] -> gcn_conv -> relu -> @ W2[64,40] -> gcn_conv -> relu
// N = 100000, E = 1600000 (derived from in_sizes at launch).
//
// R5: (a) decouple CSR fill: rank pass (atomicAdd returns within-row rank,
// coalesced write) + atomic-free fill (pos = rowptr[d] + rank[e]).
// (b) fuse gemm1 into the fill dispatch (blockIdx role split, 1:8 interleave):
// fill is memory-wait bound (R4: WRITE_SIZE=101MB = 1.6M scattered 64B lines,
// 905GB/s, VALUBusy 0.4%), gemm1 is VALU-bound -> co-residency hides gemm1.
// R3 carry-over: gemm b-loop unroll capped at 2 (full unroll => 256-VGPR
// spill, 3.1GB scratch traffic — R1/R2 lesson).

#define F0 128
#define F1 64
#define F2 40
#define SCAN_B 512
#define GEMM_BLKS 768

// ---------------- zero int counts ----------------
__global__ void k_zero(int* __restrict__ cnt, int n) {
    const int i = blockIdx.x * blockDim.x + threadIdx.x;
    if (i < n) cnt[i] = 0;
}

// ---------------- rank pass: rank[e] = running count of dst ----------------
// leaves cnt[d] = in-degree(d)
__global__ void k_rank(const int* __restrict__ ei, int* __restrict__ cnt,
                       int* __restrict__ rank, int E) {
    const int e = blockIdx.x * blockDim.x + threadIdx.x;
    if (e < E) rank[e] = atomicAdd(&cnt[ei[E + e]], 1);
}

// ---------------- invs = rsqrt(cnt+1)  (deg includes self-loop) ----------------
__global__ void k_rsqrt(const int* __restrict__ cnt, float* __restrict__ invs, int n) {
    const int i = blockIdx.x * blockDim.x + threadIdx.x;
    if (i < n) invs[i] = rsqrtf((float)(cnt[i] + 1));
}

// ---------------- scan pass 1: per-block sums ----------------
__global__ __launch_bounds__(SCAN_B) void k_bsum(const int* __restrict__ cnt,
                                                 int* __restrict__ bsum, int n) {
    __shared__ int s[SCAN_B];
    const int t = threadIdx.x;
    const int i = blockIdx.x * SCAN_B + t;
    s[t] = (i < n) ? cnt[i] : 0;
    __syncthreads();
    for (int off = SCAN_B / 2; off > 0; off >>= 1) {
        if (t < off) s[t] += s[t + off];
        __syncthreads();
    }
    if (t == 0) bsum[blockIdx.x] = s[0];
}

// ---------------- scan pass 2: exclusive scan of block sums (1 block) ----------------
__global__ __launch_bounds__(1024) void k_bscan(int* __restrict__ bsum, int nb) {
    __shared__ int s[1024];
    const int t = threadIdx.x;
    const int orig = (t < nb) ? bsum[t] : 0;
    s[t] = orig;
    __syncthreads();
    for (int off = 1; off < 1024; off <<= 1) {
        int add = (t >= off) ? s[t - off] : 0;
        __syncthreads();
        s[t] += add;
        __syncthreads();
    }
    if (t < nb) bsum[t] = s[t] - orig;   // exclusive
}

// ---------------- scan pass 3: rowptr ----------------
__global__ __launch_bounds__(SCAN_B) void k_scan3(const int* __restrict__ cnt,
                                                  const int* __restrict__ bsum,
                                                  int* __restrict__ rowptr, int n) {
    __shared__ int s[SCAN_B];
    const int t = threadIdx.x;
    const int i = blockIdx.x * SCAN_B + t;
    const int orig = (i < n) ? cnt[i] : 0;
    s[t] = orig;
    __syncthreads();
    for (int off = 1; off < SCAN_B; off <<= 1) {
        int add = (t >= off) ? s[t - off] : 0;
        __syncthreads();
        s[t] += add;
        __syncthreads();
    }
    const int excl = s[t] - orig + bsum[blockIdx.x];
    if (i < n) rowptr[i] = excl;
    if (i == n - 1) rowptr[n] = excl + orig;
}

// ---------------- fused: gemm1 (role A) + CSR fill (role B) ----------------
// role A blocks (1 of every 8, first GEMM_BLKS of them): h1 = x @ W1
// role B blocks: csr[rowptr[d]+rank[e]] = {src, invs[src]}  (no atomics)
__global__ __launch_bounds__(256) void k_gemmfill(const float* __restrict__ x,
                                                  const float* __restrict__ W,
                                                  float* __restrict__ h,
                                                  const int* __restrict__ ei,
                                                  const int* __restrict__ rank,
                                                  const int* __restrict__ rowptr,
                                                  const float* __restrict__ invs,
                                                  int2* __restrict__ csr,
                                                  int n, int E) {
    __shared__ float Wl[F0 * F1];   // 32 KB
    __shared__ float xs[32 * F0];   // 16 KB
    const int bid = blockIdx.x;
    const int tid = threadIdx.x;
    const bool is_gemm = ((bid & 7) == 0) && ((bid >> 3) < GEMM_BLKS);

    if (!is_gemm) {
        // ---- fill role ----
        const int gems_before = min((bid + 7) >> 3, GEMM_BLKS);
        const int fid = bid - gems_before;
        const int e = fid * 256 + tid;
        if (e < E) {
            const int s = ei[e];
            const int d = ei[E + e];
            const int pos = rowptr[d] + rank[e];
            csr[pos] = make_int2(s, __float_as_int(invs[s]));
        }
        return;
    }

    // ---- gemm role ----
    const int gid = bid >> 3;
    const int c = tid & 63;
    const int rq = tid >> 6;

    {
        float4* Wl4 = (float4*)Wl;
        const float4* Wg4 = (const float4*)W;
#pragma unroll
        for (int j = 0; j < (F0 * F1 / 4) / 256; ++j)
            Wl4[j * 256 + tid] = Wg4[j * 256 + tid];
    }
    __syncthreads();

    const int ntiles = (n + 31) >> 5;
    for (int tile = gid; tile < ntiles; tile += GEMM_BLKS) {
        float4* xs4w = (float4*)xs;
#pragma unroll
        for (int j = 0; j < 4; ++j) {
            int fi = j * 256 + tid;
            int row = fi >> 5;
            int rg = tile * 32 + row;
            if (rg > n - 1) rg = n - 1;
            const float4* xrow = (const float4*)(x + (long long)rg * F0);
            xs4w[fi] = xrow[fi & 31];
        }
        __syncthreads();

        float acc[8] = {0.f,0.f,0.f,0.f,0.f,0.f,0.f,0.f};
#pragma unroll 2
        for (int b = 0; b < 32; ++b) {
            const float w0 = Wl[(4 * b + 0) * F1 + c];
            const float w1 = Wl[(4 * b + 1) * F1 + c];
            const float w2 = Wl[(4 * b + 2) * F1 + c];
            const float w3 = Wl[(4 * b + 3) * F1 + c];
#pragma unroll
            for (int i = 0; i < 8; ++i) {
                float4 xv = ((const float4*)xs)[(rq * 8 + i) * 32 + b];
                acc[i] = fmaf(xv.w, w3, fmaf(xv.z, w2, fmaf(xv.y, w1, fmaf(xv.x, w0, acc[i]))));
            }
        }

#pragma unroll
        for (int i = 0; i < 8; ++i) {
            int rg = tile * 32 + rq * 8 + i;
            if (rg < n) h[(long long)rg * F1 + c] = acc[i];
        }
        __syncthreads();
    }
}

// ---------------- gemm2: h[N,40] = x[N,64] @ W[64,40] ----------------
__global__ __launch_bounds__(256) void k_gemm2(const float* __restrict__ x,
                                               const float* __restrict__ W,
                                               float* __restrict__ h, int n) {
    __shared__ float Wl[F1 * F2];   // 10 KB
    __shared__ float xs[32 * F1];   // 8 KB
    const int tid = threadIdx.x;
    const int c = tid & 63;
    const int rq = tid >> 6;

    for (int i = tid; i < F1 * F2; i += 256) Wl[i] = W[i];
    __syncthreads();

    const int ntiles = (n + 31) >> 5;
    for (int tile = blockIdx.x; tile < ntiles; tile += gridDim.x) {
        float4* xs4w = (float4*)xs;
#pragma unroll
        for (int j = 0; j < 2; ++j) {
            int fi = j * 256 + tid;
            int row = fi >> 4;
            int rg = tile * 32 + row;
            if (rg > n - 1) rg = n - 1;
            const float4* xrow = (const float4*)(x + (long long)rg * F1);
            xs4w[fi] = xrow[fi & 15];
        }
        __syncthreads();

        if (c < F2) {
            float acc[8] = {0.f,0.f,0.f,0.f,0.f,0.f,0.f,0.f};
#pragma unroll 2
            for (int b = 0; b < 16; ++b) {
                const float w0 = Wl[(4 * b + 0) * F2 + c];
                const float w1 = Wl[(4 * b + 1) * F2 + c];
                const float w2 = Wl[(4 * b + 2) * F2 + c];
                const float w3 = Wl[(4 * b + 3) * F2 + c];
#pragma unroll
                for (int i = 0; i < 8; ++i) {
                    float4 xv = ((const float4*)xs)[(rq * 8 + i) * 16 + b];
                    acc[i] = fmaf(xv.w, w3, fmaf(xv.z, w2, fmaf(xv.y, w1, fmaf(xv.x, w0, acc[i]))));
                }
            }
#pragma unroll
            for (int i = 0; i < 8; ++i) {
                int rg = tile * 32 + rq * 8 + i;
                if (rg < n) h[(long long)rg * F2 + c] = acc[i];
            }
        }
        __syncthreads();
    }
}

// ---------------- gather L1 (F=64): g[d] = relu(invd*(sum w*h[s]) + invd^2*h[d]) ----------------
__global__ __launch_bounds__(256) void k_gather64(const int* __restrict__ rowptr,
                                                  const int2* __restrict__ csr,
                                                  const float* __restrict__ invs,
                                                  const float* __restrict__ h,
                                                  float* __restrict__ g, int n) {
    const int w = (blockIdx.x * blockDim.x + threadIdx.x) >> 6;
    const int lane = threadIdx.x & 63;
    if (w >= n) return;
    const int beg = rowptr[w];
    const int end = rowptr[w + 1];
    float acc0 = 0.f, acc1 = 0.f;
    int k = beg;
    for (; k + 1 < end; k += 2) {
        const int2 p0 = csr[k];
        const int2 p1 = csr[k + 1];
        acc0 = fmaf(__int_as_float(p0.y), h[(long long)p0.x * F1 + lane], acc0);
        acc1 = fmaf(__int_as_float(p1.y), h[(long long)p1.x * F1 + lane], acc1);
    }
    if (k < end) {
        const int2 p = csr[k];
        acc0 = fmaf(__int_as_float(p.y), h[(long long)p.x * F1 + lane], acc0);
    }
    const float iv = invs[w];
    const float self = h[(long long)w * F1 + lane];
    g[(long long)w * F1 + lane] = fmaxf(fmaf(iv, acc0 + acc1, iv * iv * self), 0.f);
}

// ---------------- gather L2 (F=40) ----------------
__global__ __launch_bounds__(256) void k_gather40(const int* __restrict__ rowptr,
                                                  const int2* __restrict__ csr,
                                                  const float* __restrict__ invs,
                                                  const float* __restrict__ h,
                                                  float* __restrict__ g, int n) {
    const int w = (blockIdx.x * blockDim.x + threadIdx.x) >> 6;
    const int lane = threadIdx.x & 63;
    if (w >= n) return;
    const int beg = rowptr[w];
    const int end = rowptr[w + 1];
    float acc0 = 0.f, acc1 = 0.f;
    int k = beg;
    if (lane < F2) {
        for (; k + 1 < end; k += 2) {
            const int2 p0 = csr[k];
            const int2 p1 = csr[k + 1];
            acc0 = fmaf(__int_as_float(p0.y), h[(long long)p0.x * F2 + lane], acc0);
            acc1 = fmaf(__int_as_float(p1.y), h[(long long)p1.x * F2 + lane], acc1);
        }
        if (k < end) {
            const int2 p = csr[k];
            acc0 = fmaf(__int_as_float(p.y), h[(long long)p.x * F2 + lane], acc0);
        }
        const float iv = invs[w];
        const float self = h[(long long)w * F2 + lane];
        g[(long long)w * F2 + lane] = fmaxf(fmaf(iv, acc0 + acc1, iv * iv * self), 0.f);
    }
}

extern "C" void kernel_launch(void* const* d_in, const int* in_sizes, int n_in,
                              void* d_out, int out_size, void* d_ws, size_t ws_size,
                              hipStream_t stream) {
    const float* x  = (const float*)d_in[0];
    const int*   ei = (const int*)d_in[1];
    const float* W1 = (const float*)d_in[2];
    const float* W2 = (const float*)d_in[3];
    float* out = (float*)d_out;
    const int n = in_sizes[0] / F0;     // 100000
    const int E = in_sizes[1] / 2;      // 1600000

    // ws layout: cnt[np] | rowptr[np] | invs[np] | rank[E] | csr[E]x8B | h1[n*64] | g1[n*64] | bsum
    // (h2 aliases h1 — h1 dead after gather1)
    const size_t np = ((size_t)n + 65) & ~(size_t)63;   // room for n+1
    char* wsb = (char*)d_ws;
    int*   cnt    = (int*)wsb;
    int*   rowptr = cnt + np;
    float* invs   = (float*)(rowptr + np);
    int*   rank   = (int*)(invs + np);
    int2*  csr    = (int2*)(rank + E);
    float* h1     = (float*)(csr + E);
    float* g1     = h1 + (size_t)n * F1;
    int*   bsum   = (int*)(g1 + (size_t)n * F1);    // <= 1024 ints
    float* h2     = h1;

    const int nb = (n + SCAN_B - 1) / SCAN_B;       // 196 blocks
    const int gE = (E + 255) / 256;                 // 6250
    const int gN = (n + 255) / 256;
    const int gW = (int)(((long long)n * 64 + 255) / 256);  // 1 wave per node
    const int gFused = GEMM_BLKS + gE;              // 7018

    hipLaunchKernelGGL(k_zero,  dim3(gN), dim3(256), 0, stream, cnt, n);
    hipLaunchKernelGGL(k_rank,  dim3(gE), dim3(256), 0, stream, ei, cnt, rank, E);
    hipLaunchKernelGGL(k_rsqrt, dim3(gN), dim3(256), 0, stream, cnt, invs, n);
    hipLaunchKernelGGL(k_bsum,  dim3(nb), dim3(SCAN_B), 0, stream, cnt, bsum, n);
    hipLaunchKernelGGL(k_bscan, dim3(1),  dim3(1024), 0, stream, bsum, nb);
    hipLaunchKernelGGL(k_scan3, dim3(nb), dim3(SCAN_B), 0, stream, cnt, bsum, rowptr, n);

    hipLaunchKernelGGL(k_gemmfill, dim3(gFused), dim3(256), 0, stream,
                       x, W1, h1, ei, rank, rowptr, invs, csr, n, E);

    hipLaunchKernelGGL(k_gather64, dim3(gW), dim3(256), 0, stream, rowptr, csr, invs, h1, g1, n);
    hipLaunchKernelGGL(k_gemm2,    dim3(GEMM_BLKS), dim3(256), 0, stream, g1, W2, h2, n);
    hipLaunchKernelGGL(k_gather40, dim3(gW), dim3(256), 0, stream, rowptr, csr, invs, h2, out, n);
}

// Round 6
// 377.131 us; speedup vs baseline: 1.5724x; 1.5724x over previous
//
#include <hip/hip_runtime.h>

// GCN 2-layer: x[N,128] @ W1[128,64] -> gcn_conv -> relu -> @ W2[64,40] -> gcn_conv -> relu
// N = 100000, E = 1600000 (derived from in_sizes at launch).
//
// R6: un-fuse gemm1/fill (R5 lesson: role-split fusion shares worst-case LDS —
// fill blocks reserved 48KB they never touched, occupancy 74%->6.8%, 315us).
// Keep atomic-free fill via rank pass. NEW: CSR stores src only (4B) — fill
// loses the 1.6M random invs[s] reads, gather's sequential CSR stream halves;
// gather loads invs[s] wave-uniformly (broadcast, ~free). Fill does 4
// edges/thread for ILP.
// R3 carry-over: gemm b-loop unroll capped at 2 (full unroll => 256-VGPR
// spill, 3.1GB scratch traffic — R1/R2 lesson).

#define F0 128
#define F1 64
#define F2 40
#define SCAN_B 512
#define GEMM_BLKS 768

// ---------------- zero int counts ----------------
__global__ void k_zero(int* __restrict__ cnt, int n) {
    const int i = blockIdx.x * blockDim.x + threadIdx.x;
    if (i < n) cnt[i] = 0;
}

// ---------------- rank pass: rank[e] = within-dst running count ----------------
// leaves cnt[d] = in-degree(d)
__global__ void k_rank(const int* __restrict__ ei, int* __restrict__ cnt,
                       int* __restrict__ rank, int E) {
    const int e = blockIdx.x * blockDim.x + threadIdx.x;
    if (e < E) rank[e] = atomicAdd(&cnt[ei[E + e]], 1);
}

// ---------------- invs = rsqrt(cnt+1)  (deg includes self-loop) ----------------
__global__ void k_rsqrt(const int* __restrict__ cnt, float* __restrict__ invs, int n) {
    const int i = blockIdx.x * blockDim.x + threadIdx.x;
    if (i < n) invs[i] = rsqrtf((float)(cnt[i] + 1));
}

// ---------------- scan pass 1: per-block sums ----------------
__global__ __launch_bounds__(SCAN_B) void k_bsum(const int* __restrict__ cnt,
                                                 int* __restrict__ bsum, int n) {
    __shared__ int s[SCAN_B];
    const int t = threadIdx.x;
    const int i = blockIdx.x * SCAN_B + t;
    s[t] = (i < n) ? cnt[i] : 0;
    __syncthreads();
    for (int off = SCAN_B / 2; off > 0; off >>= 1) {
        if (t < off) s[t] += s[t + off];
        __syncthreads();
    }
    if (t == 0) bsum[blockIdx.x] = s[0];
}

// ---------------- scan pass 2: exclusive scan of block sums (1 block) ----------------
__global__ __launch_bounds__(1024) void k_bscan(int* __restrict__ bsum, int nb) {
    __shared__ int s[1024];
    const int t = threadIdx.x;
    const int orig = (t < nb) ? bsum[t] : 0;
    s[t] = orig;
    __syncthreads();
    for (int off = 1; off < 1024; off <<= 1) {
        int add = (t >= off) ? s[t - off] : 0;
        __syncthreads();
        s[t] += add;
        __syncthreads();
    }
    if (t < nb) bsum[t] = s[t] - orig;   // exclusive
}

// ---------------- scan pass 3: rowptr ----------------
__global__ __launch_bounds__(SCAN_B) void k_scan3(const int* __restrict__ cnt,
                                                  const int* __restrict__ bsum,
                                                  int* __restrict__ rowptr, int n) {
    __shared__ int s[SCAN_B];
    const int t = threadIdx.x;
    const int i = blockIdx.x * SCAN_B + t;
    const int orig = (i < n) ? cnt[i] : 0;
    s[t] = orig;
    __syncthreads();
    for (int off = 1; off < SCAN_B; off <<= 1) {
        int add = (t >= off) ? s[t - off] : 0;
        __syncthreads();
        s[t] += add;
        __syncthreads();
    }
    const int excl = s[t] - orig + bsum[blockIdx.x];
    if (i < n) rowptr[i] = excl;
    if (i == n - 1) rowptr[n] = excl + orig;
}

// ---------------- fill: csr4[rowptr[d]+rank[e]] = src (no atomics) ----------------
// 4 edges per thread (independent chains) to keep the scattered-write pipe full.
__global__ void k_fill(const int* __restrict__ ei, const int* __restrict__ rank,
                       const int* __restrict__ rowptr, int* __restrict__ csr4, int E) {
    int e = blockIdx.x * 1024 + threadIdx.x;
#pragma unroll
    for (int j = 0; j < 4; ++j, e += 256) {
        if (e < E) {
            const int s = ei[e];
            const int d = ei[E + e];
            csr4[rowptr[d] + rank[e]] = s;
        }
    }
}

// ---------------- gemm1: h[N,64] = x[N,128] @ W[128,64] ----------------
__global__ __launch_bounds__(256) void k_gemm1(const float* __restrict__ x,
                                               const float* __restrict__ W,
                                               float* __restrict__ h, int n) {
    __shared__ float Wl[F0 * F1];   // 32 KB
    __shared__ float xs[32 * F0];   // 16 KB
    const int tid = threadIdx.x;
    const int c = tid & 63;
    const int rq = tid >> 6;

    {
        float4* Wl4 = (float4*)Wl;
        const float4* Wg4 = (const float4*)W;
#pragma unroll
        for (int j = 0; j < (F0 * F1 / 4) / 256; ++j)
            Wl4[j * 256 + tid] = Wg4[j * 256 + tid];
    }
    __syncthreads();

    const int ntiles = (n + 31) >> 5;
    for (int tile = blockIdx.x; tile < ntiles; tile += gridDim.x) {
        float4* xs4w = (float4*)xs;
#pragma unroll
        for (int j = 0; j < 4; ++j) {
            int fi = j * 256 + tid;
            int row = fi >> 5;
            int rg = tile * 32 + row;
            if (rg > n - 1) rg = n - 1;
            const float4* xrow = (const float4*)(x + (long long)rg * F0);
            xs4w[fi] = xrow[fi & 31];
        }
        __syncthreads();

        float acc[8] = {0.f,0.f,0.f,0.f,0.f,0.f,0.f,0.f};
#pragma unroll 2
        for (int b = 0; b < 32; ++b) {
            const float w0 = Wl[(4 * b + 0) * F1 + c];
            const float w1 = Wl[(4 * b + 1) * F1 + c];
            const float w2 = Wl[(4 * b + 2) * F1 + c];
            const float w3 = Wl[(4 * b + 3) * F1 + c];
#pragma unroll
            for (int i = 0; i < 8; ++i) {
                float4 xv = ((const float4*)xs)[(rq * 8 + i) * 32 + b];
                acc[i] = fmaf(xv.w, w3, fmaf(xv.z, w2, fmaf(xv.y, w1, fmaf(xv.x, w0, acc[i]))));
            }
        }

#pragma unroll
        for (int i = 0; i < 8; ++i) {
            int rg = tile * 32 + rq * 8 + i;
            if (rg < n) h[(long long)rg * F1 + c] = acc[i];
        }
        __syncthreads();
    }
}

// ---------------- gemm2: h[N,40] = x[N,64] @ W[64,40] ----------------
__global__ __launch_bounds__(256) void k_gemm2(const float* __restrict__ x,
                                               const float* __restrict__ W,
                                               float* __restrict__ h, int n) {
    __shared__ float Wl[F1 * F2];   // 10 KB
    __shared__ float xs[32 * F1];   // 8 KB
    const int tid = threadIdx.x;
    const int c = tid & 63;
    const int rq = tid >> 6;

    for (int i = tid; i < F1 * F2; i += 256) Wl[i] = W[i];
    __syncthreads();

    const int ntiles = (n + 31) >> 5;
    for (int tile = blockIdx.x; tile < ntiles; tile += gridDim.x) {
        float4* xs4w = (float4*)xs;
#pragma unroll
        for (int j = 0; j < 2; ++j) {
            int fi = j * 256 + tid;
            int row = fi >> 4;
            int rg = tile * 32 + row;
            if (rg > n - 1) rg = n - 1;
            const float4* xrow = (const float4*)(x + (long long)rg * F1);
            xs4w[fi] = xrow[fi & 15];
        }
        __syncthreads();

        if (c < F2) {
            float acc[8] = {0.f,0.f,0.f,0.f,0.f,0.f,0.f,0.f};
#pragma unroll 2
            for (int b = 0; b < 16; ++b) {
                const float w0 = Wl[(4 * b + 0) * F2 + c];
                const float w1 = Wl[(4 * b + 1) * F2 + c];
                const float w2 = Wl[(4 * b + 2) * F2 + c];
                const float w3 = Wl[(4 * b + 3) * F2 + c];
#pragma unroll
                for (int i = 0; i < 8; ++i) {
                    float4 xv = ((const float4*)xs)[(rq * 8 + i) * 16 + b];
                    acc[i] = fmaf(xv.w, w3, fmaf(xv.z, w2, fmaf(xv.y, w1, fmaf(xv.x, w0, acc[i]))));
                }
            }
#pragma unroll
            for (int i = 0; i < 8; ++i) {
                int rg = tile * 32 + rq * 8 + i;
                if (rg < n) h[(long long)rg * F2 + c] = acc[i];
            }
        }
        __syncthreads();
    }
}

// ---------------- gather L1 (F=64): g[d] = relu(invd*(sum invs[s]*h[s]) + invd^2*h[d]) ----------------
__global__ __launch_bounds__(256) void k_gather64(const int* __restrict__ rowptr,
                                                  const int* __restrict__ csr4,
                                                  const float* __restrict__ invs,
                                                  const float* __restrict__ h,
                                                  float* __restrict__ g, int n) {
    const int w = (blockIdx.x * blockDim.x + threadIdx.x) >> 6;
    const int lane = threadIdx.x & 63;
    if (w >= n) return;
    const int beg = rowptr[w];
    const int end = rowptr[w + 1];
    float acc0 = 0.f, acc1 = 0.f;
    int k = beg;
    for (; k + 1 < end; k += 2) {
        const int s0 = csr4[k];
        const int s1 = csr4[k + 1];
        acc0 = fmaf(invs[s0], h[(long long)s0 * F1 + lane], acc0);
        acc1 = fmaf(invs[s1], h[(long long)s1 * F1 + lane], acc1);
    }
    if (k < end) {
        const int s0 = csr4[k];
        acc0 = fmaf(invs[s0], h[(long long)s0 * F1 + lane], acc0);
    }
    const float iv = invs[w];
    const float self = h[(long long)w * F1 + lane];
    g[(long long)w * F1 + lane] = fmaxf(fmaf(iv, acc0 + acc1, iv * iv * self), 0.f);
}

// ---------------- gather L2 (F=40) ----------------
__global__ __launch_bounds__(256) void k_gather40(const int* __restrict__ rowptr,
                                                  const int* __restrict__ csr4,
                                                  const float* __restrict__ invs,
                                                  const float* __restrict__ h,
                                                  float* __restrict__ g, int n) {
    const int w = (blockIdx.x * blockDim.x + threadIdx.x) >> 6;
    const int lane = threadIdx.x & 63;
    if (w >= n) return;
    const int beg = rowptr[w];
    const int end = rowptr[w + 1];
    float acc0 = 0.f, acc1 = 0.f;
    int k = beg;
    if (lane < F2) {
        for (; k + 1 < end; k += 2) {
            const int s0 = csr4[k];
            const int s1 = csr4[k + 1];
            acc0 = fmaf(invs[s0], h[(long long)s0 * F2 + lane], acc0);
            acc1 = fmaf(invs[s1], h[(long long)s1 * F2 + lane], acc1);
        }
        if (k < end) {
            const int s0 = csr4[k];
            acc0 = fmaf(invs[s0], h[(long long)s0 * F2 + lane], acc0);
        }
        const float iv = invs[w];
        const float self = h[(long long)w * F2 + lane];
        g[(long long)w * F2 + lane] = fmaxf(fmaf(iv, acc0 + acc1, iv * iv * self), 0.f);
    }
}

extern "C" void kernel_launch(void* const* d_in, const int* in_sizes, int n_in,
                              void* d_out, int out_size, void* d_ws, size_t ws_size,
                              hipStream_t stream) {
    const float* x  = (const float*)d_in[0];
    const int*   ei = (const int*)d_in[1];
    const float* W1 = (const float*)d_in[2];
    const float* W2 = (const float*)d_in[3];
    float* out = (float*)d_out;
    const int n = in_sizes[0] / F0;     // 100000
    const int E = in_sizes[1] / 2;      // 1600000

    // ws layout: cnt[np] | rowptr[np] | invs[np] | rank[E] | csr4[E] | h1[n*64] | g1[n*64] | bsum
    // (h2 aliases h1 — h1 dead after gather1)
    const size_t np = ((size_t)n + 65) & ~(size_t)63;   // room for n+1
    char* wsb = (char*)d_ws;
    int*   cnt    = (int*)wsb;
    int*   rowptr = cnt + np;
    float* invs   = (float*)(rowptr + np);
    int*   rank   = (int*)(invs + np);
    int*   csr4   = rank + E;
    float* h1     = (float*)(csr4 + E);
    float* g1     = h1 + (size_t)n * F1;
    int*   bsum   = (int*)(g1 + (size_t)n * F1);    // <= 1024 ints
    float* h2     = h1;

    const int nb = (n + SCAN_B - 1) / SCAN_B;       // 196 blocks
    const int gE = (E + 255) / 256;                 // 6250
    const int gN = (n + 255) / 256;
    const int gW = (int)(((long long)n * 64 + 255) / 256);  // 1 wave per node
    const int gF = (E + 1023) / 1024;               // fill: 4 edges/thread

    hipLaunchKernelGGL(k_zero,  dim3(gN), dim3(256), 0, stream, cnt, n);
    hipLaunchKernelGGL(k_rank,  dim3(gE), dim3(256), 0, stream, ei, cnt, rank, E);
    hipLaunchKernelGGL(k_rsqrt, dim3(gN), dim3(256), 0, stream, cnt, invs, n);
    hipLaunchKernelGGL(k_bsum,  dim3(nb), dim3(SCAN_B), 0, stream, cnt, bsum, n);
    hipLaunchKernelGGL(k_bscan, dim3(1),  dim3(1024), 0, stream, bsum, nb);
    hipLaunchKernelGGL(k_scan3, dim3(nb), dim3(SCAN_B), 0, stream, cnt, bsum, rowptr, n);
    hipLaunchKernelGGL(k_fill,  dim3(gF), dim3(256), 0, stream, ei, rank, rowptr, csr4, E);

    hipLaunchKernelGGL(k_gemm1,    dim3(GEMM_BLKS), dim3(256), 0, stream, x, W1, h1, n);
    hipLaunchKernelGGL(k_gather64, dim3(gW), dim3(256), 0, stream, rowptr, csr4, invs, h1, g1, n);
    hipLaunchKernelGGL(k_gemm2,    dim3(GEMM_BLKS), dim3(256), 0, stream, g1, W2, h2, n);
    hipLaunchKernelGGL(k_gather40, dim3(gW), dim3(256), 0, stream, rowptr, csr4, invs, h2, out, n);
}

// Round 7
// 365.313 us; speedup vs baseline: 1.6233x; 1.0324x over previous
//
#include <hip/hip_runtime.h>
#include <hip/hip_fp16.h>

// GCN 2-layer: x[N,128] @ W1[128,64] -> gcn_conv -> relu -> @ W2[64,40] -> gcn_conv -> relu
// N = 100000, E = 1600000 (derived from in_sizes at launch).
//
// R7: fp16 gather operands. R6 profile: k_gather64 101us, FETCH 194MB at
// ~2TB/s past-L2 (random 256B/edge gathers thrash per-XCD L2 from all 8
// XCDs) — byte-bound, not latency/VALU. h1/h2 stored as __half halves the
// per-edge gather bytes (256->128B). g1 (sequentially-streamed gemm2 input)
// stays fp32. Values are O(1) => fp16 error ~5e-4, margin 7.4e-3.
// R6 carry-over: atomic-free fill (rank pass), 4B src-only CSR.
// R5 lesson: no role-split fusion with mismatched LDS footprints.
// R3 carry-over: gemm b-loop unroll capped at 2 (full unroll => 256-VGPR
// spill, 3.1GB scratch traffic — R1/R2 lesson).

#define F0 128
#define F1 64
#define F2 40
#define SCAN_B 512
#define GEMM_BLKS 768

// ---------------- zero int counts ----------------
__global__ void k_zero(int* __restrict__ cnt, int n) {
    const int i = blockIdx.x * blockDim.x + threadIdx.x;
    if (i < n) cnt[i] = 0;
}

// ---------------- rank pass: rank[e] = within-dst running count ----------------
// leaves cnt[d] = in-degree(d)
__global__ void k_rank(const int* __restrict__ ei, int* __restrict__ cnt,
                       int* __restrict__ rank, int E) {
    const int e = blockIdx.x * blockDim.x + threadIdx.x;
    if (e < E) rank[e] = atomicAdd(&cnt[ei[E + e]], 1);
}

// ---------------- invs = rsqrt(cnt+1)  (deg includes self-loop) ----------------
__global__ void k_rsqrt(const int* __restrict__ cnt, float* __restrict__ invs, int n) {
    const int i = blockIdx.x * blockDim.x + threadIdx.x;
    if (i < n) invs[i] = rsqrtf((float)(cnt[i] + 1));
}

// ---------------- scan pass 1: per-block sums ----------------
__global__ __launch_bounds__(SCAN_B) void k_bsum(const int* __restrict__ cnt,
                                                 int* __restrict__ bsum, int n) {
    __shared__ int s[SCAN_B];
    const int t = threadIdx.x;
    const int i = blockIdx.x * SCAN_B + t;
    s[t] = (i < n) ? cnt[i] : 0;
    __syncthreads();
    for (int off = SCAN_B / 2; off > 0; off >>= 1) {
        if (t < off) s[t] += s[t + off];
        __syncthreads();
    }
    if (t == 0) bsum[blockIdx.x] = s[0];
}

// ---------------- scan pass 2: exclusive scan of block sums (1 block) ----------------
__global__ __launch_bounds__(1024) void k_bscan(int* __restrict__ bsum, int nb) {
    __shared__ int s[1024];
    const int t = threadIdx.x;
    const int orig = (t < nb) ? bsum[t] : 0;
    s[t] = orig;
    __syncthreads();
    for (int off = 1; off < 1024; off <<= 1) {
        int add = (t >= off) ? s[t - off] : 0;
        __syncthreads();
        s[t] += add;
        __syncthreads();
    }
    if (t < nb) bsum[t] = s[t] - orig;   // exclusive
}

// ---------------- scan pass 3: rowptr ----------------
__global__ __launch_bounds__(SCAN_B) void k_scan3(const int* __restrict__ cnt,
                                                  const int* __restrict__ bsum,
                                                  int* __restrict__ rowptr, int n) {
    __shared__ int s[SCAN_B];
    const int t = threadIdx.x;
    const int i = blockIdx.x * SCAN_B + t;
    const int orig = (i < n) ? cnt[i] : 0;
    s[t] = orig;
    __syncthreads();
    for (int off = 1; off < SCAN_B; off <<= 1) {
        int add = (t >= off) ? s[t - off] : 0;
        __syncthreads();
        s[t] += add;
        __syncthreads();
    }
    const int excl = s[t] - orig + bsum[blockIdx.x];
    if (i < n) rowptr[i] = excl;
    if (i == n - 1) rowptr[n] = excl + orig;
}

// ---------------- fill: csr4[rowptr[d]+rank[e]] = src (no atomics) ----------------
__global__ void k_fill(const int* __restrict__ ei, const int* __restrict__ rank,
                       const int* __restrict__ rowptr, int* __restrict__ csr4, int E) {
    int e = blockIdx.x * 1024 + threadIdx.x;
#pragma unroll
    for (int j = 0; j < 4; ++j, e += 256) {
        if (e < E) {
            const int s = ei[e];
            const int d = ei[E + e];
            csr4[rowptr[d] + rank[e]] = s;
        }
    }
}

// ---------------- gemm1: h[N,64](fp16) = x[N,128] @ W[128,64] ----------------
__global__ __launch_bounds__(256) void k_gemm1(const float* __restrict__ x,
                                               const float* __restrict__ W,
                                               __half* __restrict__ h, int n) {
    __shared__ float Wl[F0 * F1];   // 32 KB
    __shared__ float xs[32 * F0];   // 16 KB
    const int tid = threadIdx.x;
    const int c = tid & 63;
    const int rq = tid >> 6;

    {
        float4* Wl4 = (float4*)Wl;
        const float4* Wg4 = (const float4*)W;
#pragma unroll
        for (int j = 0; j < (F0 * F1 / 4) / 256; ++j)
            Wl4[j * 256 + tid] = Wg4[j * 256 + tid];
    }
    __syncthreads();

    const int ntiles = (n + 31) >> 5;
    for (int tile = blockIdx.x; tile < ntiles; tile += gridDim.x) {
        float4* xs4w = (float4*)xs;
#pragma unroll
        for (int j = 0; j < 4; ++j) {
            int fi = j * 256 + tid;
            int row = fi >> 5;
            int rg = tile * 32 + row;
            if (rg > n - 1) rg = n - 1;
            const float4* xrow = (const float4*)(x + (long long)rg * F0);
            xs4w[fi] = xrow[fi & 31];
        }
        __syncthreads();

        float acc[8] = {0.f,0.f,0.f,0.f,0.f,0.f,0.f,0.f};
#pragma unroll 2
        for (int b = 0; b < 32; ++b) {
            const float w0 = Wl[(4 * b + 0) * F1 + c];
            const float w1 = Wl[(4 * b + 1) * F1 + c];
            const float w2 = Wl[(4 * b + 2) * F1 + c];
            const float w3 = Wl[(4 * b + 3) * F1 + c];
#pragma unroll
            for (int i = 0; i < 8; ++i) {
                float4 xv = ((const float4*)xs)[(rq * 8 + i) * 32 + b];
                acc[i] = fmaf(xv.w, w3, fmaf(xv.z, w2, fmaf(xv.y, w1, fmaf(xv.x, w0, acc[i]))));
            }
        }

#pragma unroll
        for (int i = 0; i < 8; ++i) {
            int rg = tile * 32 + rq * 8 + i;
            if (rg < n) h[(long long)rg * F1 + c] = __float2half(acc[i]);
        }
        __syncthreads();
    }
}

// ---------------- gemm2: h[N,40](fp16) = g[N,64] @ W[64,40] ----------------
__global__ __launch_bounds__(256) void k_gemm2(const float* __restrict__ x,
                                               const float* __restrict__ W,
                                               __half* __restrict__ h, int n) {
    __shared__ float Wl[F1 * F2];   // 10 KB
    __shared__ float xs[32 * F1];   // 8 KB
    const int tid = threadIdx.x;
    const int c = tid & 63;
    const int rq = tid >> 6;

    for (int i = tid; i < F1 * F2; i += 256) Wl[i] = W[i];
    __syncthreads();

    const int ntiles = (n + 31) >> 5;
    for (int tile = blockIdx.x; tile < ntiles; tile += gridDim.x) {
        float4* xs4w = (float4*)xs;
#pragma unroll
        for (int j = 0; j < 2; ++j) {
            int fi = j * 256 + tid;
            int row = fi >> 4;
            int rg = tile * 32 + row;
            if (rg > n - 1) rg = n - 1;
            const float4* xrow = (const float4*)(x + (long long)rg * F1);
            xs4w[fi] = xrow[fi & 15];
        }
        __syncthreads();

        if (c < F2) {
            float acc[8] = {0.f,0.f,0.f,0.f,0.f,0.f,0.f,0.f};
#pragma unroll 2
            for (int b = 0; b < 16; ++b) {
                const float w0 = Wl[(4 * b + 0) * F2 + c];
                const float w1 = Wl[(4 * b + 1) * F2 + c];
                const float w2 = Wl[(4 * b + 2) * F2 + c];
                const float w3 = Wl[(4 * b + 3) * F2 + c];
#pragma unroll
                for (int i = 0; i < 8; ++i) {
                    float4 xv = ((const float4*)xs)[(rq * 8 + i) * 16 + b];
                    acc[i] = fmaf(xv.w, w3, fmaf(xv.z, w2, fmaf(xv.y, w1, fmaf(xv.x, w0, acc[i]))));
                }
            }
#pragma unroll
            for (int i = 0; i < 8; ++i) {
                int rg = tile * 32 + rq * 8 + i;
                if (rg < n) h[(long long)rg * F2 + c] = __float2half(acc[i]);
            }
        }
        __syncthreads();
    }
}

// ---------------- gather L1 (F=64): g[d] = relu(invd*(sum invs[s]*h[s]) + invd^2*h[d]) ----------------
__global__ __launch_bounds__(256) void k_gather64(const int* __restrict__ rowptr,
                                                  const int* __restrict__ csr4,
                                                  const float* __restrict__ invs,
                                                  const __half* __restrict__ h,
                                                  float* __restrict__ g, int n) {
    const int w = (blockIdx.x * blockDim.x + threadIdx.x) >> 6;
    const int lane = threadIdx.x & 63;
    if (w >= n) return;
    const int beg = rowptr[w];
    const int end = rowptr[w + 1];
    float acc0 = 0.f, acc1 = 0.f;
    int k = beg;
    for (; k + 1 < end; k += 2) {
        const int s0 = csr4[k];
        const int s1 = csr4[k + 1];
        acc0 = fmaf(invs[s0], __half2float(h[(long long)s0 * F1 + lane]), acc0);
        acc1 = fmaf(invs[s1], __half2float(h[(long long)s1 * F1 + lane]), acc1);
    }
    if (k < end) {
        const int s0 = csr4[k];
        acc0 = fmaf(invs[s0], __half2float(h[(long long)s0 * F1 + lane]), acc0);
    }
    const float iv = invs[w];
    const float self = __half2float(h[(long long)w * F1 + lane]);
    g[(long long)w * F1 + lane] = fmaxf(fmaf(iv, acc0 + acc1, iv * iv * self), 0.f);
}

// ---------------- gather L2 (F=40) ----------------
__global__ __launch_bounds__(256) void k_gather40(const int* __restrict__ rowptr,
                                                  const int* __restrict__ csr4,
                                                  const float* __restrict__ invs,
                                                  const __half* __restrict__ h,
                                                  float* __restrict__ g, int n) {
    const int w = (blockIdx.x * blockDim.x + threadIdx.x) >> 6;
    const int lane = threadIdx.x & 63;
    if (w >= n) return;
    const int beg = rowptr[w];
    const int end = rowptr[w + 1];
    float acc0 = 0.f, acc1 = 0.f;
    int k = beg;
    if (lane < F2) {
        for (; k + 1 < end; k += 2) {
            const int s0 = csr4[k];
            const int s1 = csr4[k + 1];
            acc0 = fmaf(invs[s0], __half2float(h[(long long)s0 * F2 + lane]), acc0);
            acc1 = fmaf(invs[s1], __half2float(h[(long long)s1 * F2 + lane]), acc1);
        }
        if (k < end) {
            const int s0 = csr4[k];
            acc0 = fmaf(invs[s0], __half2float(h[(long long)s0 * F2 + lane]), acc0);
        }
        const float iv = invs[w];
        const float self = __half2float(h[(long long)w * F2 + lane]);
        g[(long long)w * F2 + lane] = fmaxf(fmaf(iv, acc0 + acc1, iv * iv * self), 0.f);
    }
}

extern "C" void kernel_launch(void* const* d_in, const int* in_sizes, int n_in,
                              void* d_out, int out_size, void* d_ws, size_t ws_size,
                              hipStream_t stream) {
    const float* x  = (const float*)d_in[0];
    const int*   ei = (const int*)d_in[1];
    const float* W1 = (const float*)d_in[2];
    const float* W2 = (const float*)d_in[3];
    float* out = (float*)d_out;
    const int n = in_sizes[0] / F0;     // 100000
    const int E = in_sizes[1] / 2;      // 1600000

    // ws layout: cnt[np] | rowptr[np] | invs[np] | rank[E] | csr4[E] | h1h[n*64 half]
    //            | g1[n*64 f32] | bsum
    // h2h (n*40 half) aliases h1h — h1 dead after gather64.
    const size_t np = ((size_t)n + 65) & ~(size_t)63;   // room for n+1
    char* wsb = (char*)d_ws;
    int*    cnt    = (int*)wsb;
    int*    rowptr = cnt + np;
    float*  invs   = (float*)(rowptr + np);
    int*    rank   = (int*)(invs + np);
    int*    csr4   = rank + E;
    __half* h1h    = (__half*)(csr4 + E);               // n*64 halves
    float*  g1     = (float*)(h1h + (size_t)n * F1);
    int*    bsum   = (int*)(g1 + (size_t)n * F1);       // <= 1024 ints
    __half* h2h    = h1h;

    const int nb = (n + SCAN_B - 1) / SCAN_B;       // 196 blocks
    const int gE = (E + 255) / 256;                 // 6250
    const int gN = (n + 255) / 256;
    const int gW = (int)(((long long)n * 64 + 255) / 256);  // 1 wave per node
    const int gF = (E + 1023) / 1024;               // fill: 4 edges/thread

    hipLaunchKernelGGL(k_zero,  dim3(gN), dim3(256), 0, stream, cnt, n);
    hipLaunchKernelGGL(k_rank,  dim3(gE), dim3(256), 0, stream, ei, cnt, rank, E);
    hipLaunchKernelGGL(k_rsqrt, dim3(gN), dim3(256), 0, stream, cnt, invs, n);
    hipLaunchKernelGGL(k_bsum,  dim3(nb), dim3(SCAN_B), 0, stream, cnt, bsum, n);
    hipLaunchKernelGGL(k_bscan, dim3(1),  dim3(1024), 0, stream, bsum, nb);
    hipLaunchKernelGGL(k_scan3, dim3(nb), dim3(SCAN_B), 0, stream, cnt, bsum, rowptr, n);
    hipLaunchKernelGGL(k_fill,  dim3(gF), dim3(256), 0, stream, ei, rank, rowptr, csr4, E);

    hipLaunchKernelGGL(k_gemm1,    dim3(GEMM_BLKS), dim3(256), 0, stream, x, W1, h1h, n);
    hipLaunchKernelGGL(k_gather64, dim3(gW), dim3(256), 0, stream, rowptr, csr4, invs, h1h, g1, n);
    hipLaunchKernelGGL(k_gemm2,    dim3(GEMM_BLKS), dim3(256), 0, stream, g1, W2, h2h, n);
    hipLaunchKernelGGL(k_gather40, dim3(gW), dim3(256), 0, stream, rowptr, csr4, invs, h2h, out, n);
}

// Round 8
// 294.867 us; speedup vs baseline: 2.0111x; 1.2389x over previous
//
#include <hip/hip_runtime.h>
#include <hip/hip_fp16.h>

// GCN 2-layer: x[N,128] @ W1[128,64] -> gcn_conv -> relu -> @ W2[64,40] -> gcn_conv -> relu
// N = 100000, E = 1600000 (derived from in_sizes at launch).
//
// R8: gather is latency-bound (R7: FETCH halved 194->90MB, dur only 101->95us).
// (a) pre-scale h by invs[row] in gemm epilogue (hs = invs*h, fp16):
//     out_d = relu(iv_d * (sum_s hs_s + hs_d)) — kills per-edge invs[s] load
//     and multiply. (b) 8-deep gather unroll, 4 acc chains -> 8 outstanding
//     VMEM per wave (was 2).
// R7 carry-over: fp16 gather operands (halves random-gather bytes).
// R6 carry-over: atomic-free fill (rank pass), 4B src-only CSR.
// R5 lesson: no role-split fusion with mismatched LDS footprints.
// R3 carry-over: gemm b-loop unroll capped at 2 (full unroll => 256-VGPR
// spill, 3.1GB scratch traffic — R1/R2 lesson).

#define F0 128
#define F1 64
#define F2 40
#define SCAN_B 512
#define GEMM_BLKS 768

// ---------------- zero int counts ----------------
__global__ void k_zero(int* __restrict__ cnt, int n) {
    const int i = blockIdx.x * blockDim.x + threadIdx.x;
    if (i < n) cnt[i] = 0;
}

// ---------------- rank pass: rank[e] = within-dst running count ----------------
__global__ void k_rank(const int* __restrict__ ei, int* __restrict__ cnt,
                       int* __restrict__ rank, int E) {
    const int e = blockIdx.x * blockDim.x + threadIdx.x;
    if (e < E) rank[e] = atomicAdd(&cnt[ei[E + e]], 1);
}

// ---------------- invs = rsqrt(cnt+1)  (deg includes self-loop) ----------------
__global__ void k_rsqrt(const int* __restrict__ cnt, float* __restrict__ invs, int n) {
    const int i = blockIdx.x * blockDim.x + threadIdx.x;
    if (i < n) invs[i] = rsqrtf((float)(cnt[i] + 1));
}

// ---------------- scan pass 1: per-block sums ----------------
__global__ __launch_bounds__(SCAN_B) void k_bsum(const int* __restrict__ cnt,
                                                 int* __restrict__ bsum, int n) {
    __shared__ int s[SCAN_B];
    const int t = threadIdx.x;
    const int i = blockIdx.x * SCAN_B + t;
    s[t] = (i < n) ? cnt[i] : 0;
    __syncthreads();
    for (int off = SCAN_B / 2; off > 0; off >>= 1) {
        if (t < off) s[t] += s[t + off];
        __syncthreads();
    }
    if (t == 0) bsum[blockIdx.x] = s[0];
}

// ---------------- scan pass 2: exclusive scan of block sums (1 block) ----------------
__global__ __launch_bounds__(1024) void k_bscan(int* __restrict__ bsum, int nb) {
    __shared__ int s[1024];
    const int t = threadIdx.x;
    const int orig = (t < nb) ? bsum[t] : 0;
    s[t] = orig;
    __syncthreads();
    for (int off = 1; off < 1024; off <<= 1) {
        int add = (t >= off) ? s[t - off] : 0;
        __syncthreads();
        s[t] += add;
        __syncthreads();
    }
    if (t < nb) bsum[t] = s[t] - orig;   // exclusive
}

// ---------------- scan pass 3: rowptr ----------------
__global__ __launch_bounds__(SCAN_B) void k_scan3(const int* __restrict__ cnt,
                                                  const int* __restrict__ bsum,
                                                  int* __restrict__ rowptr, int n) {
    __shared__ int s[SCAN_B];
    const int t = threadIdx.x;
    const int i = blockIdx.x * SCAN_B + t;
    const int orig = (i < n) ? cnt[i] : 0;
    s[t] = orig;
    __syncthreads();
    for (int off = 1; off < SCAN_B; off <<= 1) {
        int add = (t >= off) ? s[t - off] : 0;
        __syncthreads();
        s[t] += add;
        __syncthreads();
    }
    const int excl = s[t] - orig + bsum[blockIdx.x];
    if (i < n) rowptr[i] = excl;
    if (i == n - 1) rowptr[n] = excl + orig;
}

// ---------------- fill: csr4[rowptr[d]+rank[e]] = src (no atomics) ----------------
__global__ void k_fill(const int* __restrict__ ei, const int* __restrict__ rank,
                       const int* __restrict__ rowptr, int* __restrict__ csr4, int E) {
    int e = blockIdx.x * 1024 + threadIdx.x;
#pragma unroll
    for (int j = 0; j < 4; ++j, e += 256) {
        if (e < E) {
            const int s = ei[e];
            const int d = ei[E + e];
            csr4[rowptr[d] + rank[e]] = s;
        }
    }
}

// ---------------- gemm1: hs[N,64](fp16) = invs[row] * (x[N,128] @ W[128,64]) ----------------
__global__ __launch_bounds__(256) void k_gemm1(const float* __restrict__ x,
                                               const float* __restrict__ W,
                                               const float* __restrict__ invs,
                                               __half* __restrict__ h, int n) {
    __shared__ float Wl[F0 * F1];   // 32 KB
    __shared__ float xs[32 * F0];   // 16 KB
    const int tid = threadIdx.x;
    const int c = tid & 63;
    const int rq = tid >> 6;

    {
        float4* Wl4 = (float4*)Wl;
        const float4* Wg4 = (const float4*)W;
#pragma unroll
        for (int j = 0; j < (F0 * F1 / 4) / 256; ++j)
            Wl4[j * 256 + tid] = Wg4[j * 256 + tid];
    }
    __syncthreads();

    const int ntiles = (n + 31) >> 5;
    for (int tile = blockIdx.x; tile < ntiles; tile += gridDim.x) {
        float4* xs4w = (float4*)xs;
#pragma unroll
        for (int j = 0; j < 4; ++j) {
            int fi = j * 256 + tid;
            int row = fi >> 5;
            int rg = tile * 32 + row;
            if (rg > n - 1) rg = n - 1;
            const float4* xrow = (const float4*)(x + (long long)rg * F0);
            xs4w[fi] = xrow[fi & 31];
        }
        __syncthreads();

        float acc[8] = {0.f,0.f,0.f,0.f,0.f,0.f,0.f,0.f};
#pragma unroll 2
        for (int b = 0; b < 32; ++b) {
            const float w0 = Wl[(4 * b + 0) * F1 + c];
            const float w1 = Wl[(4 * b + 1) * F1 + c];
            const float w2 = Wl[(4 * b + 2) * F1 + c];
            const float w3 = Wl[(4 * b + 3) * F1 + c];
#pragma unroll
            for (int i = 0; i < 8; ++i) {
                float4 xv = ((const float4*)xs)[(rq * 8 + i) * 32 + b];
                acc[i] = fmaf(xv.w, w3, fmaf(xv.z, w2, fmaf(xv.y, w1, fmaf(xv.x, w0, acc[i]))));
            }
        }

#pragma unroll
        for (int i = 0; i < 8; ++i) {
            int rg = tile * 32 + rq * 8 + i;
            if (rg < n) h[(long long)rg * F1 + c] = __float2half(acc[i] * invs[rg]);
        }
        __syncthreads();
    }
}

// ---------------- gemm2: hs[N,40](fp16) = invs[row] * (g[N,64] @ W[64,40]) ----------------
__global__ __launch_bounds__(256) void k_gemm2(const float* __restrict__ x,
                                               const float* __restrict__ W,
                                               const float* __restrict__ invs,
                                               __half* __restrict__ h, int n) {
    __shared__ float Wl[F1 * F2];   // 10 KB
    __shared__ float xs[32 * F1];   // 8 KB
    const int tid = threadIdx.x;
    const int c = tid & 63;
    const int rq = tid >> 6;

    for (int i = tid; i < F1 * F2; i += 256) Wl[i] = W[i];
    __syncthreads();

    const int ntiles = (n + 31) >> 5;
    for (int tile = blockIdx.x; tile < ntiles; tile += gridDim.x) {
        float4* xs4w = (float4*)xs;
#pragma unroll
        for (int j = 0; j < 2; ++j) {
            int fi = j * 256 + tid;
            int row = fi >> 4;
            int rg = tile * 32 + row;
            if (rg > n - 1) rg = n - 1;
            const float4* xrow = (const float4*)(x + (long long)rg * F1);
            xs4w[fi] = xrow[fi & 15];
        }
        __syncthreads();

        if (c < F2) {
            float acc[8] = {0.f,0.f,0.f,0.f,0.f,0.f,0.f,0.f};
#pragma unroll 2
            for (int b = 0; b < 16; ++b) {
                const float w0 = Wl[(4 * b + 0) * F2 + c];
                const float w1 = Wl[(4 * b + 1) * F2 + c];
                const float w2 = Wl[(4 * b + 2) * F2 + c];
                const float w3 = Wl[(4 * b + 3) * F2 + c];
#pragma unroll
                for (int i = 0; i < 8; ++i) {
                    float4 xv = ((const float4*)xs)[(rq * 8 + i) * 16 + b];
                    acc[i] = fmaf(xv.w, w3, fmaf(xv.z, w2, fmaf(xv.y, w1, fmaf(xv.x, w0, acc[i]))));
                }
            }
#pragma unroll
            for (int i = 0; i < 8; ++i) {
                int rg = tile * 32 + rq * 8 + i;
                if (rg < n) h[(long long)rg * F2 + c] = __float2half(acc[i] * invs[rg]);
            }
        }
        __syncthreads();
    }
}

// ---------------- gather L1 (F=64): g[d] = relu(iv_d*(sum hs[s] + hs[d])) ----------------
// 8-deep unroll: 8 outstanding gathers per wave, 4 independent acc chains.
__global__ __launch_bounds__(256) void k_gather64(const int* __restrict__ rowptr,
                                                  const int* __restrict__ csr4,
                                                  const float* __restrict__ invs,
                                                  const __half* __restrict__ h,
                                                  float* __restrict__ g, int n) {
    const int w = (blockIdx.x * blockDim.x + threadIdx.x) >> 6;
    const int lane = threadIdx.x & 63;
    if (w >= n) return;
    const int beg = rowptr[w];
    const int end = rowptr[w + 1];
    float acc0 = 0.f, acc1 = 0.f, acc2 = 0.f, acc3 = 0.f;
    int k = beg;
    for (; k + 8 <= end; k += 8) {
        const int s0 = csr4[k+0], s1 = csr4[k+1], s2 = csr4[k+2], s3 = csr4[k+3];
        const int s4 = csr4[k+4], s5 = csr4[k+5], s6 = csr4[k+6], s7 = csr4[k+7];
        const float v0 = __half2float(h[(long long)s0 * F1 + lane]);
        const float v1 = __half2float(h[(long long)s1 * F1 + lane]);
        const float v2 = __half2float(h[(long long)s2 * F1 + lane]);
        const float v3 = __half2float(h[(long long)s3 * F1 + lane]);
        const float v4 = __half2float(h[(long long)s4 * F1 + lane]);
        const float v5 = __half2float(h[(long long)s5 * F1 + lane]);
        const float v6 = __half2float(h[(long long)s6 * F1 + lane]);
        const float v7 = __half2float(h[(long long)s7 * F1 + lane]);
        acc0 += v0 + v4; acc1 += v1 + v5; acc2 += v2 + v6; acc3 += v3 + v7;
    }
    for (; k + 2 <= end; k += 2) {
        const int s0 = csr4[k], s1 = csr4[k+1];
        acc0 += __half2float(h[(long long)s0 * F1 + lane]);
        acc1 += __half2float(h[(long long)s1 * F1 + lane]);
    }
    if (k < end) {
        const int s0 = csr4[k];
        acc0 += __half2float(h[(long long)s0 * F1 + lane]);
    }
    const float iv = invs[w];
    const float self = __half2float(h[(long long)w * F1 + lane]);
    g[(long long)w * F1 + lane] = fmaxf(iv * (((acc0 + acc1) + (acc2 + acc3)) + self), 0.f);
}

// ---------------- gather L2 (F=40) ----------------
__global__ __launch_bounds__(256) void k_gather40(const int* __restrict__ rowptr,
                                                  const int* __restrict__ csr4,
                                                  const float* __restrict__ invs,
                                                  const __half* __restrict__ h,
                                                  float* __restrict__ g, int n) {
    const int w = (blockIdx.x * blockDim.x + threadIdx.x) >> 6;
    const int lane = threadIdx.x & 63;
    if (w >= n) return;
    const int beg = rowptr[w];
    const int end = rowptr[w + 1];
    float acc0 = 0.f, acc1 = 0.f, acc2 = 0.f, acc3 = 0.f;
    int k = beg;
    if (lane < F2) {
        for (; k + 8 <= end; k += 8) {
            const int s0 = csr4[k+0], s1 = csr4[k+1], s2 = csr4[k+2], s3 = csr4[k+3];
            const int s4 = csr4[k+4], s5 = csr4[k+5], s6 = csr4[k+6], s7 = csr4[k+7];
            const float v0 = __half2float(h[(long long)s0 * F2 + lane]);
            const float v1 = __half2float(h[(long long)s1 * F2 + lane]);
            const float v2 = __half2float(h[(long long)s2 * F2 + lane]);
            const float v3 = __half2float(h[(long long)s3 * F2 + lane]);
            const float v4 = __half2float(h[(long long)s4 * F2 + lane]);
            const float v5 = __half2float(h[(long long)s5 * F2 + lane]);
            const float v6 = __half2float(h[(long long)s6 * F2 + lane]);
            const float v7 = __half2float(h[(long long)s7 * F2 + lane]);
            acc0 += v0 + v4; acc1 += v1 + v5; acc2 += v2 + v6; acc3 += v3 + v7;
        }
        for (; k + 2 <= end; k += 2) {
            const int s0 = csr4[k], s1 = csr4[k+1];
            acc0 += __half2float(h[(long long)s0 * F2 + lane]);
            acc1 += __half2float(h[(long long)s1 * F2 + lane]);
        }
        if (k < end) {
            const int s0 = csr4[k];
            acc0 += __half2float(h[(long long)s0 * F2 + lane]);
        }
        const float iv = invs[w];
        const float self = __half2float(h[(long long)w * F2 + lane]);
        g[(long long)w * F2 + lane] = fmaxf(iv * (((acc0 + acc1) + (acc2 + acc3)) + self), 0.f);
    }
}

extern "C" void kernel_launch(void* const* d_in, const int* in_sizes, int n_in,
                              void* d_out, int out_size, void* d_ws, size_t ws_size,
                              hipStream_t stream) {
    const float* x  = (const float*)d_in[0];
    const int*   ei = (const int*)d_in[1];
    const float* W1 = (const float*)d_in[2];
    const float* W2 = (const float*)d_in[3];
    float* out = (float*)d_out;
    const int n = in_sizes[0] / F0;     // 100000
    const int E = in_sizes[1] / 2;      // 1600000

    // ws layout: cnt[np] | rowptr[np] | invs[np] | rank[E] | csr4[E] | h1h[n*64 half]
    //            | g1[n*64 f32] | bsum     (h2h aliases h1h)
    const size_t np = ((size_t)n + 65) & ~(size_t)63;   // room for n+1
    char* wsb = (char*)d_ws;
    int*    cnt    = (int*)wsb;
    int*    rowptr = cnt + np;
    float*  invs   = (float*)(rowptr + np);
    int*    rank   = (int*)(invs + np);
    int*    csr4   = rank + E;
    __half* h1h    = (__half*)(csr4 + E);               // n*64 halves
    float*  g1     = (float*)(h1h + (size_t)n * F1);
    int*    bsum   = (int*)(g1 + (size_t)n * F1);       // <= 1024 ints
    __half* h2h    = h1h;

    const int nb = (n + SCAN_B - 1) / SCAN_B;       // 196 blocks
    const int gE = (E + 255) / 256;                 // 6250
    const int gN = (n + 255) / 256;
    const int gW = (int)(((long long)n * 64 + 255) / 256);  // 1 wave per node
    const int gF = (E + 1023) / 1024;               // fill: 4 edges/thread

    hipLaunchKernelGGL(k_zero,  dim3(gN), dim3(256), 0, stream, cnt, n);
    hipLaunchKernelGGL(k_rank,  dim3(gE), dim3(256), 0, stream, ei, cnt, rank, E);
    hipLaunchKernelGGL(k_rsqrt, dim3(gN), dim3(256), 0, stream, cnt, invs, n);
    hipLaunchKernelGGL(k_bsum,  dim3(nb), dim3(SCAN_B), 0, stream, cnt, bsum, n);
    hipLaunchKernelGGL(k_bscan, dim3(1),  dim3(1024), 0, stream, bsum, nb);
    hipLaunchKernelGGL(k_scan3, dim3(nb), dim3(SCAN_B), 0, stream, cnt, bsum, rowptr, n);
    hipLaunchKernelGGL(k_fill,  dim3(gF), dim3(256), 0, stream, ei, rank, rowptr, csr4, E);

    hipLaunchKernelGGL(k_gemm1,    dim3(GEMM_BLKS), dim3(256), 0, stream, x, W1, invs, h1h, n);
    hipLaunchKernelGGL(k_gather64, dim3(gW), dim3(256), 0, stream, rowptr, csr4, invs, h1h, g1, n);
    hipLaunchKernelGGL(k_gemm2,    dim3(GEMM_BLKS), dim3(256), 0, stream, g1, W2, invs, h2h, n);
    hipLaunchKernelGGL(k_gather40, dim3(gW), dim3(256), 0, stream, rowptr, csr4, invs, h2h, out, n);
}

// Round 9
// 293.325 us; speedup vs baseline: 2.0217x; 1.0053x over previous
//
#include <hip/hip_runtime.h>
#include <hip/hip_fp16.h>

// GCN 2-layer: x[N,128] @ W1[128,64] -> gcn_conv -> relu -> @ W2[64,40] -> gcn_conv -> relu
// N = 100000, E = 1600000 (derived from in_sizes at launch).
//
// R9: pad cnt to 1 counter per 64B line (stride 16 ints). R8 profile: k_rank
// 66us, WRITE_SIZE 56MB vs 6.4MB logical => cnt line churn; 256 RMWs/line
// serialize at the coherence point. Padding -> 100k lines, ~16 RMW/line.
// Also fused rsqrt into bsum (one fewer launch).
// R8 carry-over: pre-scaled hs=invs*h (no per-edge invs load), 8-deep gather.
// R7 carry-over: fp16 gather operands. R6: atomic-free fill via rank pass,
// 4B src-only CSR. R5 lesson: no role-split fusion with mismatched LDS.
// R3 lesson: gemm b-loop unroll capped at 2 (else 256-VGPR spill).

#define F0 128
#define F1 64
#define F2 40
#define SCAN_B 512
#define GEMM_BLKS 768
#define CPAD 16   // ints per counter slot (64B line)

// ---------------- zero padded counters ----------------
__global__ void k_zero(int* __restrict__ cntp, int n) {
    const int i = blockIdx.x * blockDim.x + threadIdx.x;
    if (i < n) cntp[(size_t)i << 4] = 0;
}

// ---------------- rank pass: rank[e] = within-dst running count ----------------
// leaves cntp[d*16] = in-degree(d). One counter per 64B line.
__global__ void k_rank(const int* __restrict__ ei, int* __restrict__ cntp,
                       int* __restrict__ rank, int E) {
    const int e = blockIdx.x * blockDim.x + threadIdx.x;
    if (e < E) rank[e] = atomicAdd(&cntp[(size_t)ei[E + e] << 4], 1);
}

// ---------------- fused: invs = rsqrt(deg+1); per-block sums of deg ----------------
__global__ __launch_bounds__(SCAN_B) void k_rsqrt_bsum(const int* __restrict__ cntp,
                                                       float* __restrict__ invs,
                                                       int* __restrict__ bsum, int n) {
    __shared__ int s[SCAN_B];
    const int t = threadIdx.x;
    const int i = blockIdx.x * SCAN_B + t;
    int c = 0;
    if (i < n) {
        c = cntp[(size_t)i << 4];
        invs[i] = rsqrtf((float)(c + 1));
    }
    s[t] = c;
    __syncthreads();
    for (int off = SCAN_B / 2; off > 0; off >>= 1) {
        if (t < off) s[t] += s[t + off];
        __syncthreads();
    }
    if (t == 0) bsum[blockIdx.x] = s[0];
}

// ---------------- scan pass 2: exclusive scan of block sums (1 block) ----------------
__global__ __launch_bounds__(1024) void k_bscan(int* __restrict__ bsum, int nb) {
    __shared__ int s[1024];
    const int t = threadIdx.x;
    const int orig = (t < nb) ? bsum[t] : 0;
    s[t] = orig;
    __syncthreads();
    for (int off = 1; off < 1024; off <<= 1) {
        int add = (t >= off) ? s[t - off] : 0;
        __syncthreads();
        s[t] += add;
        __syncthreads();
    }
    if (t < nb) bsum[t] = s[t] - orig;   // exclusive
}

// ---------------- scan pass 3: rowptr ----------------
__global__ __launch_bounds__(SCAN_B) void k_scan3(const int* __restrict__ cntp,
                                                  const int* __restrict__ bsum,
                                                  int* __restrict__ rowptr, int n) {
    __shared__ int s[SCAN_B];
    const int t = threadIdx.x;
    const int i = blockIdx.x * SCAN_B + t;
    const int orig = (i < n) ? cntp[(size_t)i << 4] : 0;
    s[t] = orig;
    __syncthreads();
    for (int off = 1; off < SCAN_B; off <<= 1) {
        int add = (t >= off) ? s[t - off] : 0;
        __syncthreads();
        s[t] += add;
        __syncthreads();
    }
    const int excl = s[t] - orig + bsum[blockIdx.x];
    if (i < n) rowptr[i] = excl;
    if (i == n - 1) rowptr[n] = excl + orig;
}

// ---------------- fill: csr4[rowptr[d]+rank[e]] = src (no atomics) ----------------
__global__ void k_fill(const int* __restrict__ ei, const int* __restrict__ rank,
                       const int* __restrict__ rowptr, int* __restrict__ csr4, int E) {
    int e = blockIdx.x * 1024 + threadIdx.x;
#pragma unroll
    for (int j = 0; j < 4; ++j, e += 256) {
        if (e < E) {
            const int s = ei[e];
            const int d = ei[E + e];
            csr4[rowptr[d] + rank[e]] = s;
        }
    }
}

// ---------------- gemm1: hs[N,64](fp16) = invs[row] * (x[N,128] @ W[128,64]) ----------------
__global__ __launch_bounds__(256) void k_gemm1(const float* __restrict__ x,
                                               const float* __restrict__ W,
                                               const float* __restrict__ invs,
                                               __half* __restrict__ h, int n) {
    __shared__ float Wl[F0 * F1];   // 32 KB
    __shared__ float xs[32 * F0];   // 16 KB
    const int tid = threadIdx.x;
    const int c = tid & 63;
    const int rq = tid >> 6;

    {
        float4* Wl4 = (float4*)Wl;
        const float4* Wg4 = (const float4*)W;
#pragma unroll
        for (int j = 0; j < (F0 * F1 / 4) / 256; ++j)
            Wl4[j * 256 + tid] = Wg4[j * 256 + tid];
    }
    __syncthreads();

    const int ntiles = (n + 31) >> 5;
    for (int tile = blockIdx.x; tile < ntiles; tile += gridDim.x) {
        float4* xs4w = (float4*)xs;
#pragma unroll
        for (int j = 0; j < 4; ++j) {
            int fi = j * 256 + tid;
            int row = fi >> 5;
            int rg = tile * 32 + row;
            if (rg > n - 1) rg = n - 1;
            const float4* xrow = (const float4*)(x + (long long)rg * F0);
            xs4w[fi] = xrow[fi & 31];
        }
        __syncthreads();

        float acc[8] = {0.f,0.f,0.f,0.f,0.f,0.f,0.f,0.f};
#pragma unroll 2
        for (int b = 0; b < 32; ++b) {
            const float w0 = Wl[(4 * b + 0) * F1 + c];
            const float w1 = Wl[(4 * b + 1) * F1 + c];
            const float w2 = Wl[(4 * b + 2) * F1 + c];
            const float w3 = Wl[(4 * b + 3) * F1 + c];
#pragma unroll
            for (int i = 0; i < 8; ++i) {
                float4 xv = ((const float4*)xs)[(rq * 8 + i) * 32 + b];
                acc[i] = fmaf(xv.w, w3, fmaf(xv.z, w2, fmaf(xv.y, w1, fmaf(xv.x, w0, acc[i]))));
            }
        }

#pragma unroll
        for (int i = 0; i < 8; ++i) {
            int rg = tile * 32 + rq * 8 + i;
            if (rg < n) h[(long long)rg * F1 + c] = __float2half(acc[i] * invs[rg]);
        }
        __syncthreads();
    }
}

// ---------------- gemm2: hs[N,40](fp16) = invs[row] * (g[N,64] @ W[64,40]) ----------------
__global__ __launch_bounds__(256) void k_gemm2(const float* __restrict__ x,
                                               const float* __restrict__ W,
                                               const float* __restrict__ invs,
                                               __half* __restrict__ h, int n) {
    __shared__ float Wl[F1 * F2];   // 10 KB
    __shared__ float xs[32 * F1];   // 8 KB
    const int tid = threadIdx.x;
    const int c = tid & 63;
    const int rq = tid >> 6;

    for (int i = tid; i < F1 * F2; i += 256) Wl[i] = W[i];
    __syncthreads();

    const int ntiles = (n + 31) >> 5;
    for (int tile = blockIdx.x; tile < ntiles; tile += gridDim.x) {
        float4* xs4w = (float4*)xs;
#pragma unroll
        for (int j = 0; j < 2; ++j) {
            int fi = j * 256 + tid;
            int row = fi >> 4;
            int rg = tile * 32 + row;
            if (rg > n - 1) rg = n - 1;
            const float4* xrow = (const float4*)(x + (long long)rg * F1);
            xs4w[fi] = xrow[fi & 15];
        }
        __syncthreads();

        if (c < F2) {
            float acc[8] = {0.f,0.f,0.f,0.f,0.f,0.f,0.f,0.f};
#pragma unroll 2
            for (int b = 0; b < 16; ++b) {
                const float w0 = Wl[(4 * b + 0) * F2 + c];
                const float w1 = Wl[(4 * b + 1) * F2 + c];
                const float w2 = Wl[(4 * b + 2) * F2 + c];
                const float w3 = Wl[(4 * b + 3) * F2 + c];
#pragma unroll
                for (int i = 0; i < 8; ++i) {
                    float4 xv = ((const float4*)xs)[(rq * 8 + i) * 16 + b];
                    acc[i] = fmaf(xv.w, w3, fmaf(xv.z, w2, fmaf(xv.y, w1, fmaf(xv.x, w0, acc[i]))));
                }
            }
#pragma unroll
            for (int i = 0; i < 8; ++i) {
                int rg = tile * 32 + rq * 8 + i;
                if (rg < n) h[(long long)rg * F2 + c] = __float2half(acc[i] * invs[rg]);
            }
        }
        __syncthreads();
    }
}

// ---------------- gather L1 (F=64): g[d] = relu(iv_d*(sum hs[s] + hs[d])) ----------------
__global__ __launch_bounds__(256) void k_gather64(const int* __restrict__ rowptr,
                                                  const int* __restrict__ csr4,
                                                  const float* __restrict__ invs,
                                                  const __half* __restrict__ h,
                                                  float* __restrict__ g, int n) {
    const int w = (blockIdx.x * blockDim.x + threadIdx.x) >> 6;
    const int lane = threadIdx.x & 63;
    if (w >= n) return;
    const int beg = rowptr[w];
    const int end = rowptr[w + 1];
    float acc0 = 0.f, acc1 = 0.f, acc2 = 0.f, acc3 = 0.f;
    int k = beg;
    for (; k + 8 <= end; k += 8) {
        const int s0 = csr4[k+0], s1 = csr4[k+1], s2 = csr4[k+2], s3 = csr4[k+3];
        const int s4 = csr4[k+4], s5 = csr4[k+5], s6 = csr4[k+6], s7 = csr4[k+7];
        const float v0 = __half2float(h[(long long)s0 * F1 + lane]);
        const float v1 = __half2float(h[(long long)s1 * F1 + lane]);
        const float v2 = __half2float(h[(long long)s2 * F1 + lane]);
        const float v3 = __half2float(h[(long long)s3 * F1 + lane]);
        const float v4 = __half2float(h[(long long)s4 * F1 + lane]);
        const float v5 = __half2float(h[(long long)s5 * F1 + lane]);
        const float v6 = __half2float(h[(long long)s6 * F1 + lane]);
        const float v7 = __half2float(h[(long long)s7 * F1 + lane]);
        acc0 += v0 + v4; acc1 += v1 + v5; acc2 += v2 + v6; acc3 += v3 + v7;
    }
    for (; k + 2 <= end; k += 2) {
        const int s0 = csr4[k], s1 = csr4[k+1];
        acc0 += __half2float(h[(long long)s0 * F1 + lane]);
        acc1 += __half2float(h[(long long)s1 * F1 + lane]);
    }
    if (k < end) {
        const int s0 = csr4[k];
        acc0 += __half2float(h[(long long)s0 * F1 + lane]);
    }
    const float iv = invs[w];
    const float self = __half2float(h[(long long)w * F1 + lane]);
    g[(long long)w * F1 + lane] = fmaxf(iv * (((acc0 + acc1) + (acc2 + acc3)) + self), 0.f);
}

// ---------------- gather L2 (F=40) ----------------
__global__ __launch_bounds__(256) void k_gather40(const int* __restrict__ rowptr,
                                                  const int* __restrict__ csr4,
                                                  const float* __restrict__ invs,
                                                  const __half* __restrict__ h,
                                                  float* __restrict__ g, int n) {
    const int w = (blockIdx.x * blockDim.x + threadIdx.x) >> 6;
    const int lane = threadIdx.x & 63;
    if (w >= n) return;
    const int beg = rowptr[w];
    const int end = rowptr[w + 1];
    float acc0 = 0.f, acc1 = 0.f, acc2 = 0.f, acc3 = 0.f;
    int k = beg;
    if (lane < F2) {
        for (; k + 8 <= end; k += 8) {
            const int s0 = csr4[k+0], s1 = csr4[k+1], s2 = csr4[k+2], s3 = csr4[k+3];
            const int s4 = csr4[k+4], s5 = csr4[k+5], s6 = csr4[k+6], s7 = csr4[k+7];
            const float v0 = __half2float(h[(long long)s0 * F2 + lane]);
            const float v1 = __half2float(h[(long long)s1 * F2 + lane]);
            const float v2 = __half2float(h[(long long)s2 * F2 + lane]);
            const float v3 = __half2float(h[(long long)s3 * F2 + lane]);
            const float v4 = __half2float(h[(long long)s4 * F2 + lane]);
            const float v5 = __half2float(h[(long long)s5 * F2 + lane]);
            const float v6 = __half2float(h[(long long)s6 * F2 + lane]);
            const float v7 = __half2float(h[(long long)s7 * F2 + lane]);
            acc0 += v0 + v4; acc1 += v1 + v5; acc2 += v2 + v6; acc3 += v3 + v7;
        }
        for (; k + 2 <= end; k += 2) {
            const int s0 = csr4[k], s1 = csr4[k+1];
            acc0 += __half2float(h[(long long)s0 * F2 + lane]);
            acc1 += __half2float(h[(long long)s1 * F2 + lane]);
        }
        if (k < end) {
            const int s0 = csr4[k];
            acc0 += __half2float(h[(long long)s0 * F2 + lane]);
        }
        const float iv = invs[w];
        const float self = __half2float(h[(long long)w * F2 + lane]);
        g[(long long)w * F2 + lane] = fmaxf(iv * (((acc0 + acc1) + (acc2 + acc3)) + self), 0.f);
    }
}

extern "C" void kernel_launch(void* const* d_in, const int* in_sizes, int n_in,
                              void* d_out, int out_size, void* d_ws, size_t ws_size,
                              hipStream_t stream) {
    const float* x  = (const float*)d_in[0];
    const int*   ei = (const int*)d_in[1];
    const float* W1 = (const float*)d_in[2];
    const float* W2 = (const float*)d_in[3];
    float* out = (float*)d_out;
    const int n = in_sizes[0] / F0;     // 100000
    const int E = in_sizes[1] / 2;      // 1600000

    // ws layout: cntp[np*16] | rowptr[np] | invs[np] | rank[E] | csr4[E]
    //            | h1h[n*64 half] | g1[n*64 f32] | bsum     (h2h aliases h1h)
    const size_t np = ((size_t)n + 65) & ~(size_t)63;   // room for n+1
    char* wsb = (char*)d_ws;
    int*    cntp   = (int*)wsb;                         // padded: 1 counter / 64B
    int*    rowptr = cntp + np * CPAD;
    float*  invs   = (float*)(rowptr + np);
    int*    rank   = (int*)(invs + np);
    int*    csr4   = rank + E;
    __half* h1h    = (__half*)(csr4 + E);               // n*64 halves
    float*  g1     = (float*)(h1h + (size_t)n * F1);
    int*    bsum   = (int*)(g1 + (size_t)n * F1);       // <= 1024 ints
    __half* h2h    = h1h;

    const int nb = (n + SCAN_B - 1) / SCAN_B;       // 196 blocks
    const int gE = (E + 255) / 256;                 // 6250
    const int gN = (n + 255) / 256;
    const int gW = (int)(((long long)n * 64 + 255) / 256);  // 1 wave per node
    const int gF = (E + 1023) / 1024;               // fill: 4 edges/thread

    hipLaunchKernelGGL(k_zero,       dim3(gN), dim3(256), 0, stream, cntp, n);
    hipLaunchKernelGGL(k_rank,       dim3(gE), dim3(256), 0, stream, ei, cntp, rank, E);
    hipLaunchKernelGGL(k_rsqrt_bsum, dim3(nb), dim3(SCAN_B), 0, stream, cntp, invs, bsum, n);
    hipLaunchKernelGGL(k_bscan,      dim3(1),  dim3(1024), 0, stream, bsum, nb);
    hipLaunchKernelGGL(k_scan3,      dim3(nb), dim3(SCAN_B), 0, stream, cntp, bsum, rowptr, n);
    hipLaunchKernelGGL(k_fill,       dim3(gF), dim3(256), 0, stream, ei, rank, rowptr, csr4, E);

    hipLaunchKernelGGL(k_gemm1,    dim3(GEMM_BLKS), dim3(256), 0, stream, x, W1, invs, h1h, n);
    hipLaunchKernelGGL(k_gather64, dim3(gW), dim3(256), 0, stream, rowptr, csr4, invs, h1h, g1, n);
    hipLaunchKernelGGL(k_gemm2,    dim3(GEMM_BLKS), dim3(256), 0, stream, g1, W2, invs, h2h, n);
    hipLaunchKernelGGL(k_gather40, dim3(gW), dim3(256), 0, stream, rowptr, csr4, invs, h2h, out, n);
}

// Round 10
// 249.264 us; speedup vs baseline: 2.3790x; 1.1768x over previous
//
#include <hip/hip_runtime.h>
#include <hip/hip_fp16.h>

// GCN 2-layer: x[N,128] @ W1[128,64] -> gcn_conv -> relu -> @ W2[64,40] -> gcn_conv -> relu
// N = 100000, E = 1600000 (derived from in_sizes at launch).
//
// R10: overlap rank's fabric-bound atomics with gemm1's VALU work via a
// SAME-FOOTPRINT role split (768 blocks, 48KB LDS each, 3/CU): bid%3==2 ->
// rank role (256 blocks, pure atomicAdd-return issue), else gemm role (512).
// R9 lesson (null): padding cnt to 1/line changed nothing — atomic cost is a
// fixed ~32B fabric packet per op (24G/s), not line contention. Padding
// reverted. R5 lesson refined: fusion is fine iff roles share the same
// LDS/occupancy budget (R5 failed: 6250 LDS-less blocks behind 48KB cap).
// R8 carry-over: pre-scaled hs=invs*h, 8-deep gather unroll.
// R7: fp16 gather operands. R6: atomic-free fill via rank, 4B src-only CSR.
// R3 lesson: gemm b-loop unroll capped at 2 (else 256-VGPR spill).

#define F0 128
#define F1 64
#define F2 40
#define SCAN_B 512
#define GEMM_BLKS 768          // total fused grid; 512 gemm + 256 rank
#define NRANK (GEMM_BLKS / 3)  // 256 rank-role blocks

// ---------------- zero int counts ----------------
__global__ void k_zero(int* __restrict__ cnt, int n) {
    const int i = blockIdx.x * blockDim.x + threadIdx.x;
    if (i < n) cnt[i] = 0;
}

// ---------------- fused: gemm1 (2 of 3 blocks) + rank pass (1 of 3) ----------------
// gemm role: hs1[N,64](fp16) = invs-pending... h = x @ W1 (scaled later? no —
//   scaling needs invs which needs rank counts! NOTE: gemm1 writes UNSCALED
//   h here; the scale by invs[row] moves to gather64's epilogue... see below.
// Wait: R8's pre-scale used invs at gemm epilogue. invs isn't known until rank
// completes — and rank completes only at THIS kernel's end. So gemm role
// writes raw h (fp16); gather64 loads invs[s] per edge?? NO — we keep the
// pre-scale by doing it in a tiny separate pass fused into k_fill (h1h *= invs
// row-wise, n*64 elems, ~4us) after rsqrt is known. See k_fill_scale.
__global__ __launch_bounds__(256) void k_gemmrank(const float* __restrict__ x,
                                                  const float* __restrict__ W,
                                                  __half* __restrict__ h,
                                                  const int* __restrict__ ei,
                                                  int* __restrict__ cnt,
                                                  int* __restrict__ rank,
                                                  int n, int E) {
    __shared__ float Wl[F0 * F1];   // 32 KB
    __shared__ float xs[32 * F0];   // 16 KB
    const int bid = blockIdx.x;
    const int tid = threadIdx.x;

    if ((bid % 3) == 2) {
        // ---- rank role: 256 blocks, grid-stride over edges ----
        const int rb = bid / 3;                 // 0..255
        const int stride = NRANK * 256;         // 65536
#pragma unroll 4
        for (int e = rb * 256 + tid; e < E; e += stride)
            rank[e] = atomicAdd(&cnt[ei[E + e]], 1);
        return;
    }

    // ---- gemm role: gid in [0,512) ----
    const int gid = bid - bid / 3;
    const int c = tid & 63;
    const int rq = tid >> 6;

    {
        float4* Wl4 = (float4*)Wl;
        const float4* Wg4 = (const float4*)W;
#pragma unroll
        for (int j = 0; j < (F0 * F1 / 4) / 256; ++j)
            Wl4[j * 256 + tid] = Wg4[j * 256 + tid];
    }
    __syncthreads();

    const int NG = GEMM_BLKS - NRANK;           // 512
    const int ntiles = (n + 31) >> 5;
    for (int tile = gid; tile < ntiles; tile += NG) {
        float4* xs4w = (float4*)xs;
#pragma unroll
        for (int j = 0; j < 4; ++j) {
            int fi = j * 256 + tid;
            int row = fi >> 5;
            int rg = tile * 32 + row;
            if (rg > n - 1) rg = n - 1;
            const float4* xrow = (const float4*)(x + (long long)rg * F0);
            xs4w[fi] = xrow[fi & 31];
        }
        __syncthreads();

        float acc[8] = {0.f,0.f,0.f,0.f,0.f,0.f,0.f,0.f};
#pragma unroll 2
        for (int b = 0; b < 32; ++b) {
            const float w0 = Wl[(4 * b + 0) * F1 + c];
            const float w1 = Wl[(4 * b + 1) * F1 + c];
            const float w2 = Wl[(4 * b + 2) * F1 + c];
            const float w3 = Wl[(4 * b + 3) * F1 + c];
#pragma unroll
            for (int i = 0; i < 8; ++i) {
                float4 xv = ((const float4*)xs)[(rq * 8 + i) * 32 + b];
                acc[i] = fmaf(xv.w, w3, fmaf(xv.z, w2, fmaf(xv.y, w1, fmaf(xv.x, w0, acc[i]))));
            }
        }

#pragma unroll
        for (int i = 0; i < 8; ++i) {
            int rg = tile * 32 + rq * 8 + i;
            if (rg < n) h[(long long)rg * F1 + c] = __float2half(acc[i]);
        }
        __syncthreads();
    }
}

// ---------------- fused: invs = rsqrt(deg+1); per-block sums of deg ----------------
__global__ __launch_bounds__(SCAN_B) void k_rsqrt_bsum(const int* __restrict__ cnt,
                                                       float* __restrict__ invs,
                                                       int* __restrict__ bsum, int n) {
    __shared__ int s[SCAN_B];
    const int t = threadIdx.x;
    const int i = blockIdx.x * SCAN_B + t;
    int c = 0;
    if (i < n) {
        c = cnt[i];
        invs[i] = rsqrtf((float)(c + 1));
    }
    s[t] = c;
    __syncthreads();
    for (int off = SCAN_B / 2; off > 0; off >>= 1) {
        if (t < off) s[t] += s[t + off];
        __syncthreads();
    }
    if (t == 0) bsum[blockIdx.x] = s[0];
}

// ---------------- scan pass 2: exclusive scan of block sums (1 block) ----------------
__global__ __launch_bounds__(1024) void k_bscan(int* __restrict__ bsum, int nb) {
    __shared__ int s[1024];
    const int t = threadIdx.x;
    const int orig = (t < nb) ? bsum[t] : 0;
    s[t] = orig;
    __syncthreads();
    for (int off = 1; off < 1024; off <<= 1) {
        int add = (t >= off) ? s[t - off] : 0;
        __syncthreads();
        s[t] += add;
        __syncthreads();
    }
    if (t < nb) bsum[t] = s[t] - orig;   // exclusive
}

// ---------------- scan pass 3: rowptr ----------------
__global__ __launch_bounds__(SCAN_B) void k_scan3(const int* __restrict__ cnt,
                                                  const int* __restrict__ bsum,
                                                  int* __restrict__ rowptr, int n) {
    __shared__ int s[SCAN_B];
    const int t = threadIdx.x;
    const int i = blockIdx.x * SCAN_B + t;
    const int orig = (i < n) ? cnt[i] : 0;
    s[t] = orig;
    __syncthreads();
    for (int off = 1; off < SCAN_B; off <<= 1) {
        int add = (t >= off) ? s[t - off] : 0;
        __syncthreads();
        s[t] += add;
        __syncthreads();
    }
    const int excl = s[t] - orig + bsum[blockIdx.x];
    if (i < n) rowptr[i] = excl;
    if (i == n - 1) rowptr[n] = excl + orig;
}

// ---------------- fill + h-scale: csr4[rowptr[d]+rank[e]] = src; h *= invs row-wise ----------------
// First gFILL blocks do the CSR fill; remaining blocks scale h1h by invs[row]
// (the R8 pre-scale, deferred here because invs wasn't known at gemm time).
__global__ void k_fill_scale(const int* __restrict__ ei, const int* __restrict__ rank,
                             const int* __restrict__ rowptr, int* __restrict__ csr4,
                             __half* __restrict__ h, const float* __restrict__ invs,
                             int E, int n, int gFILL) {
    const int bid = blockIdx.x;
    const int tid = threadIdx.x;
    if (bid < gFILL) {
        int e = bid * 1024 + tid;
#pragma unroll
        for (int j = 0; j < 4; ++j, e += 256) {
            if (e < E) {
                const int s = ei[e];
                const int d = ei[E + e];
                csr4[rowptr[d] + rank[e]] = s;
            }
        }
    } else {
        // scale role: h[r][c] *= invs[r], vectorized 4 halves (64-bit) per thread
        const int fb = bid - gFILL;
        const long long total4 = (long long)n * F1 / 4;   // n*16 half4 groups
        long long i4 = (long long)fb * 256 + tid;
        const long long stride = (long long)2048 * 256;   // fixed scale grid 2048 blocks
        for (; i4 < total4; i4 += stride) {
            const int r = (int)(i4 >> 4);                 // 16 half4 per row
            const float iv = invs[r];
            __half2* hp = (__half2*)h + i4 * 2;
            __half2 a = hp[0], b = hp[1];
            float2 af = __half22float2(a), bf = __half22float2(b);
            af.x *= iv; af.y *= iv; bf.x *= iv; bf.y *= iv;
            hp[0] = __float22half2_rn(af);
            hp[1] = __float22half2_rn(bf);
        }
    }
}

// ---------------- gemm2: hs[N,40](fp16) = invs[row] * (g[N,64] @ W[64,40]) ----------------
__global__ __launch_bounds__(256) void k_gemm2(const float* __restrict__ x,
                                               const float* __restrict__ W,
                                               const float* __restrict__ invs,
                                               __half* __restrict__ h, int n) {
    __shared__ float Wl[F1 * F2];   // 10 KB
    __shared__ float xs[32 * F1];   // 8 KB
    const int tid = threadIdx.x;
    const int c = tid & 63;
    const int rq = tid >> 6;

    for (int i = tid; i < F1 * F2; i += 256) Wl[i] = W[i];
    __syncthreads();

    const int ntiles = (n + 31) >> 5;
    for (int tile = blockIdx.x; tile < ntiles; tile += gridDim.x) {
        float4* xs4w = (float4*)xs;
#pragma unroll
        for (int j = 0; j < 2; ++j) {
            int fi = j * 256 + tid;
            int row = fi >> 4;
            int rg = tile * 32 + row;
            if (rg > n - 1) rg = n - 1;
            const float4* xrow = (const float4*)(x + (long long)rg * F1);
            xs4w[fi] = xrow[fi & 15];
        }
        __syncthreads();

        if (c < F2) {
            float acc[8] = {0.f,0.f,0.f,0.f,0.f,0.f,0.f,0.f};
#pragma unroll 2
            for (int b = 0; b < 16; ++b) {
                const float w0 = Wl[(4 * b + 0) * F2 + c];
                const float w1 = Wl[(4 * b + 1) * F2 + c];
                const float w2 = Wl[(4 * b + 2) * F2 + c];
                const float w3 = Wl[(4 * b + 3) * F2 + c];
#pragma unroll
                for (int i = 0; i < 8; ++i) {
                    float4 xv = ((const float4*)xs)[(rq * 8 + i) * 16 + b];
                    acc[i] = fmaf(xv.w, w3, fmaf(xv.z, w2, fmaf(xv.y, w1, fmaf(xv.x, w0, acc[i]))));
                }
            }
#pragma unroll
            for (int i = 0; i < 8; ++i) {
                int rg = tile * 32 + rq * 8 + i;
                if (rg < n) h[(long long)rg * F2 + c] = __float2half(acc[i] * invs[rg]);
            }
        }
        __syncthreads();
    }
}

// ---------------- gather L1 (F=64): g[d] = relu(iv_d*(sum hs[s] + hs[d])) ----------------
__global__ __launch_bounds__(256) void k_gather64(const int* __restrict__ rowptr,
                                                  const int* __restrict__ csr4,
                                                  const float* __restrict__ invs,
                                                  const __half* __restrict__ h,
                                                  float* __restrict__ g, int n) {
    const int w = (blockIdx.x * blockDim.x + threadIdx.x) >> 6;
    const int lane = threadIdx.x & 63;
    if (w >= n) return;
    const int beg = rowptr[w];
    const int end = rowptr[w + 1];
    float acc0 = 0.f, acc1 = 0.f, acc2 = 0.f, acc3 = 0.f;
    int k = beg;
    for (; k + 8 <= end; k += 8) {
        const int s0 = csr4[k+0], s1 = csr4[k+1], s2 = csr4[k+2], s3 = csr4[k+3];
        const int s4 = csr4[k+4], s5 = csr4[k+5], s6 = csr4[k+6], s7 = csr4[k+7];
        const float v0 = __half2float(h[(long long)s0 * F1 + lane]);
        const float v1 = __half2float(h[(long long)s1 * F1 + lane]);
        const float v2 = __half2float(h[(long long)s2 * F1 + lane]);
        const float v3 = __half2float(h[(long long)s3 * F1 + lane]);
        const float v4 = __half2float(h[(long long)s4 * F1 + lane]);
        const float v5 = __half2float(h[(long long)s5 * F1 + lane]);
        const float v6 = __half2float(h[(long long)s6 * F1 + lane]);
        const float v7 = __half2float(h[(long long)s7 * F1 + lane]);
        acc0 += v0 + v4; acc1 += v1 + v5; acc2 += v2 + v6; acc3 += v3 + v7;
    }
    for (; k + 2 <= end; k += 2) {
        const int s0 = csr4[k], s1 = csr4[k+1];
        acc0 += __half2float(h[(long long)s0 * F1 + lane]);
        acc1 += __half2float(h[(long long)s1 * F1 + lane]);
    }
    if (k < end) {
        const int s0 = csr4[k];
        acc0 += __half2float(h[(long long)s0 * F1 + lane]);
    }
    const float iv = invs[w];
    const float self = __half2float(h[(long long)w * F1 + lane]);
    g[(long long)w * F1 + lane] = fmaxf(iv * (((acc0 + acc1) + (acc2 + acc3)) + self), 0.f);
}

// ---------------- gather L2 (F=40) ----------------
__global__ __launch_bounds__(256) void k_gather40(const int* __restrict__ rowptr,
                                                  const int* __restrict__ csr4,
                                                  const float* __restrict__ invs,
                                                  const __half* __restrict__ h,
                                                  float* __restrict__ g, int n) {
    const int w = (blockIdx.x * blockDim.x + threadIdx.x) >> 6;
    const int lane = threadIdx.x & 63;
    if (w >= n) return;
    const int beg = rowptr[w];
    const int end = rowptr[w + 1];
    float acc0 = 0.f, acc1 = 0.f, acc2 = 0.f, acc3 = 0.f;
    int k = beg;
    if (lane < F2) {
        for (; k + 8 <= end; k += 8) {
            const int s0 = csr4[k+0], s1 = csr4[k+1], s2 = csr4[k+2], s3 = csr4[k+3];
            const int s4 = csr4[k+4], s5 = csr4[k+5], s6 = csr4[k+6], s7 = csr4[k+7];
            const float v0 = __half2float(h[(long long)s0 * F2 + lane]);
            const float v1 = __half2float(h[(long long)s1 * F2 + lane]);
            const float v2 = __half2float(h[(long long)s2 * F2 + lane]);
            const float v3 = __half2float(h[(long long)s3 * F2 + lane]);
            const float v4 = __half2float(h[(long long)s4 * F2 + lane]);
            const float v5 = __half2float(h[(long long)s5 * F2 + lane]);
            const float v6 = __half2float(h[(long long)s6 * F2 + lane]);
            const float v7 = __half2float(h[(long long)s7 * F2 + lane]);
            acc0 += v0 + v4; acc1 += v1 + v5; acc2 += v2 + v6; acc3 += v3 + v7;
        }
        for (; k + 2 <= end; k += 2) {
            const int s0 = csr4[k], s1 = csr4[k+1];
            acc0 += __half2float(h[(long long)s0 * F2 + lane]);
            acc1 += __half2float(h[(long long)s1 * F2 + lane]);
        }
        if (k < end) {
            const int s0 = csr4[k];
            acc0 += __half2float(h[(long long)s0 * F2 + lane]);
        }
        const float iv = invs[w];
        const float self = __half2float(h[(long long)w * F2 + lane]);
        g[(long long)w * F2 + lane] = fmaxf(iv * (((acc0 + acc1) + (acc2 + acc3)) + self), 0.f);
    }
}

extern "C" void kernel_launch(void* const* d_in, const int* in_sizes, int n_in,
                              void* d_out, int out_size, void* d_ws, size_t ws_size,
                              hipStream_t stream) {
    const float* x  = (const float*)d_in[0];
    const int*   ei = (const int*)d_in[1];
    const float* W1 = (const float*)d_in[2];
    const float* W2 = (const float*)d_in[3];
    float* out = (float*)d_out;
    const int n = in_sizes[0] / F0;     // 100000
    const int E = in_sizes[1] / 2;      // 1600000

    // ws layout: cnt[np] | rowptr[np] | invs[np] | rank[E] | csr4[E]
    //            | h1h[n*64 half] | g1[n*64 f32] | bsum     (h2h aliases h1h)
    const size_t np = ((size_t)n + 65) & ~(size_t)63;   // room for n+1
    char* wsb = (char*)d_ws;
    int*    cnt    = (int*)wsb;
    int*    rowptr = cnt + np;
    float*  invs   = (float*)(rowptr + np);
    int*    rank   = (int*)(invs + np);
    int*    csr4   = rank + E;
    __half* h1h    = (__half*)(csr4 + E);               // n*64 halves
    float*  g1     = (float*)(h1h + (size_t)n * F1);
    int*    bsum   = (int*)(g1 + (size_t)n * F1);       // <= 1024 ints
    __half* h2h    = h1h;

    const int nb = (n + SCAN_B - 1) / SCAN_B;       // 196 blocks
    const int gN = (n + 255) / 256;
    const int gW = (int)(((long long)n * 64 + 255) / 256);  // 1 wave per node
    const int gFILL = (E + 1023) / 1024;            // fill: 4 edges/thread
    const int gFS = gFILL + 2048;                   // fill + scale roles

    hipLaunchKernelGGL(k_zero,      dim3(gN), dim3(256), 0, stream, cnt, n);
    hipLaunchKernelGGL(k_gemmrank,  dim3(GEMM_BLKS), dim3(256), 0, stream,
                       x, W1, h1h, ei, cnt, rank, n, E);
    hipLaunchKernelGGL(k_rsqrt_bsum, dim3(nb), dim3(SCAN_B), 0, stream, cnt, invs, bsum, n);
    hipLaunchKernelGGL(k_bscan,      dim3(1),  dim3(1024), 0, stream, bsum, nb);
    hipLaunchKernelGGL(k_scan3,      dim3(nb), dim3(SCAN_B), 0, stream, cnt, bsum, rowptr, n);
    hipLaunchKernelGGL(k_fill_scale, dim3(gFS), dim3(256), 0, stream,
                       ei, rank, rowptr, csr4, h1h, invs, E, n, gFILL);

    hipLaunchKernelGGL(k_gather64, dim3(gW), dim3(256), 0, stream, rowptr, csr4, invs, h1h, g1, n);
    hipLaunchKernelGGL(k_gemm2,    dim3(GEMM_BLKS), dim3(256), 0, stream, g1, W2, invs, h2h, n);
    hipLaunchKernelGGL(k_gather40, dim3(gW), dim3(256), 0, stream, rowptr, csr4, invs, h2h, out, n);
}